// Round 6
// baseline (686.901 us; speedup 1.0000x reference)
//
#include <hip/hip_runtime.h>
#include <hip/hip_bf16.h>
#include <stdint.h>

typedef __attribute__((ext_vector_type(8))) short bf16x8;
typedef __attribute__((ext_vector_type(4))) float f32x4;

#define NN 8192
#define DF 256
#define KSPLIT 2
#define KCH (NN / KSPLIT)   // 4096
#define KSTEPS (KCH / 32)   // 128

static __device__ __forceinline__ unsigned short f2bf(float f) {
  union { float f; unsigned u; } v; v.f = f;
  unsigned r = (v.u + 0x7FFFu + ((v.u >> 16) & 1u)) >> 16;
  return (unsigned short)r;
}

// ---- kernel 1: h2[j] = dot(input[j,:], A[0:256])  (one wave per row)
__global__ void k_h2(const float* __restrict__ input, const float* __restrict__ A,
                     float* __restrict__ h2) {
  int gw = (blockIdx.x * blockDim.x + threadIdx.x) >> 6;
  int lane = threadIdx.x & 63;
  float4 x = *reinterpret_cast<const float4*>(&input[(size_t)gw * DF + lane * 4]);
  float4 a = *reinterpret_cast<const float4*>(&A[lane * 4]);
  float p = x.x * a.x + x.y * a.y + x.z * a.z + x.w * a.w;
#pragma unroll
  for (int off = 32; off > 0; off >>= 1) p += __shfl_down(p, off, 64);
  if (lane == 0) h2[gw] = p;
}

// ---- kernel 2: per-block redundant global max + s = exp(h2 - M), fp32+bf16
__global__ void k_s(const float* __restrict__ h2, float* __restrict__ sF,
                    unsigned short* __restrict__ sT) {
  __shared__ float sm[4];
  float m = -3.0e38f;
  for (int i = threadIdx.x; i < NN; i += 256) m = fmaxf(m, h2[i]);
#pragma unroll
  for (int off = 32; off > 0; off >>= 1) m = fmaxf(m, __shfl_down(m, off, 64));
  int lane = threadIdx.x & 63, wid = threadIdx.x >> 6;
  if (lane == 0) sm[wid] = m;
  __syncthreads();
  float M = fmaxf(fmaxf(sm[0], sm[1]), fmaxf(sm[2], sm[3]));
  int j = blockIdx.x * 256 + threadIdx.x;
  float s = expf(h2[j] - M);
  sF[j] = s;
  sT[j] = f2bf(s);
}

// ---- kernel 3: XsT[c][j] = bf16(sF[j] * input[j][c])  row-major [DF][NN]
__global__ void k_xst(const float* __restrict__ input, const float* __restrict__ sF,
                      unsigned short* __restrict__ XsT) {
  int b = blockIdx.x;
  int jb = b >> 2, cb = b & 3;
  int t = threadIdx.x;
  int j0 = jb * 64 + (t & 15) * 4;
  int c0 = cb * 64 + (t >> 4) * 4;
  float4 x[4]; float s[4];
#pragma unroll
  for (int ii = 0; ii < 4; ii++) {
    x[ii] = *reinterpret_cast<const float4*>(&input[(size_t)(j0 + ii) * DF + c0]);
    s[ii] = sF[j0 + ii];
  }
#pragma unroll
  for (int q = 0; q < 4; q++) {
    ushort4 o;
    o.x = f2bf(reinterpret_cast<const float*>(&x[0])[q] * s[0]);
    o.y = f2bf(reinterpret_cast<const float*>(&x[1])[q] * s[1]);
    o.z = f2bf(reinterpret_cast<const float*>(&x[2])[q] * s[2]);
    o.w = f2bf(reinterpret_cast<const float*>(&x[3])[q] * s[3]);
    *reinterpret_cast<ushort4*>(&XsT[(size_t)(c0 + q) * NN + j0]) = o;
  }
}

// ---- kernel 4: numerator partials (+ fused denominator), pure-register MFMA.
// No LDS, no barriers. Block = 4 waves sharing one 16-row adj panel (adj hits
// HBM once; sibling waves' identical loads are L1 hits). Wave owns 64 cols.
__global__ __launch_bounds__(256, 4) void k_gemm(
    const int* __restrict__ adj, const unsigned short* __restrict__ XsT,
    const unsigned short* __restrict__ sT, float* __restrict__ C0,
    float* __restrict__ C1, float* __restrict__ denomPart) {
  const int tid = threadIdx.x;
  const int lane = tid & 63;
  const int wid = tid >> 6;        // col-group 0..3
  const int l15 = lane & 15;
  const int l4 = lane >> 4;        // 0..3

  const int bx = blockIdx.x;
  const int kidx = bx & 1;
  const int rg = bx >> 1;          // 0..511
  const int r0 = rg * 16;
  const int kbeg = kidx * KCH;
  float* __restrict__ Cout = kidx ? C1 : C0;

  // A: lane's fragment rows/k-slots.  row = r0 + l15, k = l4*8 + 0..7
  const int* pA = adj + (size_t)(r0 + l15) * NN + kbeg + l4 * 8;
  // B: 4 col-fragments. col = wid*64 + n*16 + l15, same k slots
  const unsigned short* pB0 = XsT + (size_t)(wid * 64 + 0 * 16 + l15) * NN + kbeg + l4 * 8;
  const unsigned short* pB1 = XsT + (size_t)(wid * 64 + 1 * 16 + l15) * NN + kbeg + l4 * 8;
  const unsigned short* pB2 = XsT + (size_t)(wid * 64 + 2 * 16 + l15) * NN + kbeg + l4 * 8;
  const unsigned short* pB3 = XsT + (size_t)(wid * 64 + 3 * 16 + l15) * NN + kbeg + l4 * 8;
  const unsigned short* pS = sT + kbeg + l4 * 8;

  f32x4 acc0 = {0,0,0,0}, acc1 = {0,0,0,0}, acc2 = {0,0,0,0}, acc3 = {0,0,0,0};
  f32x4 accD = {0,0,0,0};

#pragma unroll 2
  for (int t = 0; t < KSTEPS; ++t) {
    const int ko = t * 32;
    int4 lo = *reinterpret_cast<const int4*>(pA + ko);
    int4 hi = *reinterpret_cast<const int4*>(pA + ko + 4);
    bf16x8 b0 = *reinterpret_cast<const bf16x8*>(pB0 + ko);
    bf16x8 b1 = *reinterpret_cast<const bf16x8*>(pB1 + ko);
    bf16x8 b2 = *reinterpret_cast<const bf16x8*>(pB2 + ko);
    bf16x8 b3 = *reinterpret_cast<const bf16x8*>(pB3 + ko);
    union { unsigned u[4]; bf16x8 v; } A;
    A.u[0] = (unsigned)(lo.x + (lo.y << 16)) * 0x3F80u;
    A.u[1] = (unsigned)(lo.z + (lo.w << 16)) * 0x3F80u;
    A.u[2] = (unsigned)(hi.x + (hi.y << 16)) * 0x3F80u;
    A.u[3] = (unsigned)(hi.z + (hi.w << 16)) * 0x3F80u;
    acc0 = __builtin_amdgcn_mfma_f32_16x16x32_bf16(A.v, b0, acc0, 0, 0, 0);
    acc1 = __builtin_amdgcn_mfma_f32_16x16x32_bf16(A.v, b1, acc1, 0, 0, 0);
    acc2 = __builtin_amdgcn_mfma_f32_16x16x32_bf16(A.v, b2, acc2, 0, 0, 0);
    acc3 = __builtin_amdgcn_mfma_f32_16x16x32_bf16(A.v, b3, acc3, 0, 0, 0);
    if (wid == 0) {
      bf16x8 sv = *reinterpret_cast<const bf16x8*>(pS + ko);
      accD = __builtin_amdgcn_mfma_f32_16x16x32_bf16(A.v, sv, accD, 0, 0, 0);
    }
  }

  // epilogue: C/D layout col = lane&15, row = (lane>>4)*4 + q
  const int row0 = r0 + l4 * 4;
  const int col0 = wid * 64 + l15;
#pragma unroll
  for (int q = 0; q < 4; q++) {
    float* cr = Cout + (size_t)(row0 + q) * DF + col0;
    cr[0]  = acc0[q];
    cr[16] = acc1[q];
    cr[32] = acc2[q];
    cr[48] = acc3[q];
  }
  if (wid == 0 && l15 == 0) {
#pragma unroll
    for (int q = 0; q < 4; q++)
      denomPart[kidx * NN + row0 + q] = accD[q];
  }
}

// ---- kernel 5: out = (C0 + C1) / denom   (in place: C0 == d_out)
__global__ void k_norm(float* __restrict__ out, const float* __restrict__ C1,
                       const float* __restrict__ denomPart) {
  int e4 = blockIdx.x * 256 + threadIdx.x;
  size_t base = (size_t)e4 * 4;
  int row = (int)(base >> 8);
  float4 a = *reinterpret_cast<const float4*>(&out[base]);
  float4 b = *reinterpret_cast<const float4*>(&C1[base]);
  float inv = 1.0f / (denomPart[row] + denomPart[NN + row]);
  float4 r;
  r.x = (a.x + b.x) * inv;
  r.y = (a.y + b.y) * inv;
  r.z = (a.z + b.z) * inv;
  r.w = (a.w + b.w) * inv;
  *reinterpret_cast<float4*>(&out[base]) = r;
}

extern "C" void kernel_launch(void* const* d_in, const int* in_sizes, int n_in,
                              void* d_out, int out_size, void* d_ws, size_t ws_size,
                              hipStream_t stream) {
  const float* input = (const float*)d_in[0];
  const int* adj = (const int*)d_in[1];
  const float* A = (const float*)d_in[2];
  float* out = (float*)d_out;

  char* ws = (char*)d_ws;
  float* h2 = (float*)(ws + 0);                         // 32 KB
  float* sF = (float*)(ws + 33024);                     // 32 KB
  unsigned short* sT = (unsigned short*)(ws + 65792);   // 16 KB
  unsigned short* XsT = (unsigned short*)(ws + 82176);  // 4 MB row-major [DF][NN]
  float* C1 = (float*)(ws + 82176 + 4194304);           // 8 MB
  float* denomPart = (float*)(ws + 82176 + 4194304 + 8388608);  // 64 KB

  k_h2<<<dim3(NN / 4), dim3(256), 0, stream>>>(input, A, h2);
  k_s<<<dim3(NN / 256), dim3(256), 0, stream>>>(h2, sF, sT);
  k_xst<<<dim3((NN / 64) * (DF / 64)), dim3(256), 0, stream>>>(input, sF, XsT);
  k_gemm<<<dim3((NN / 16) * KSPLIT), dim3(256), 0, stream>>>(adj, XsT, sT, out, C1,
                                                             denomPart);
  k_norm<<<dim3(NN * DF / 1024), dim3(256), 0, stream>>>(out, C1, denomPart);
}

// Round 8
// 557.958 us; speedup vs baseline: 1.2311x; 1.2311x over previous
//
#include <hip/hip_runtime.h>
#include <hip/hip_bf16.h>
#include <stdint.h>

typedef __attribute__((ext_vector_type(8))) short bf16x8;
typedef __attribute__((ext_vector_type(4))) float f32x4;

#define NN 8192
#define DF 256
#define KSPLIT 2
#define KCH (NN / KSPLIT)   // 4096
#define KSTEPS (KCH / 32)   // 128

static __device__ __forceinline__ unsigned short f2bf(float f) {
  union { float f; unsigned u; } v; v.f = f;
  unsigned r = (v.u + 0x7FFFu + ((v.u >> 16) & 1u)) >> 16;
  return (unsigned short)r;
}

// ---- kernel 1: fused h2 -> s=exp(h2) (no shift; cancels in normalize) -> XsT
// block = 256 threads handles 64 source rows j.
__global__ __launch_bounds__(256) void k_pre(const float* __restrict__ input,
                                             const float* __restrict__ A,
                                             unsigned short* __restrict__ sT,
                                             unsigned short* __restrict__ XsT) {
  __shared__ float s_sh[64];
  const int j0 = blockIdx.x * 64;
  const int lane = threadIdx.x & 63;
  const int wid = threadIdx.x >> 6;

  float4 a = *reinterpret_cast<const float4*>(&A[lane * 4]);
#pragma unroll 4
  for (int r = 0; r < 16; ++r) {
    int row = j0 + wid * 16 + r;
    float4 x = *reinterpret_cast<const float4*>(&input[(size_t)row * DF + lane * 4]);
    float p = x.x * a.x + x.y * a.y + x.z * a.z + x.w * a.w;
#pragma unroll
    for (int off = 1; off < 64; off <<= 1) p += __shfl_xor(p, off, 64);
    float s = expf(p);
    if (lane == 0) {
      s_sh[wid * 16 + r] = s;
      sT[row] = f2bf(s);
    }
  }
  __syncthreads();

  const int t = threadIdx.x;
  const int j0l = (t & 15) * 4;
  const int c00 = (t >> 4) * 4;
  float sv[4];
#pragma unroll
  for (int ii = 0; ii < 4; ii++) sv[ii] = s_sh[j0l + ii];
#pragma unroll
  for (int cb = 0; cb < 4; ++cb) {
    int c0 = cb * 64 + c00;
    float4 x[4];
#pragma unroll
    for (int ii = 0; ii < 4; ii++)
      x[ii] = *reinterpret_cast<const float4*>(
          &input[(size_t)(j0 + j0l + ii) * DF + c0]);
#pragma unroll
    for (int q = 0; q < 4; q++) {
      ushort4 o;
      o.x = f2bf(reinterpret_cast<const float*>(&x[0])[q] * sv[0]);
      o.y = f2bf(reinterpret_cast<const float*>(&x[1])[q] * sv[1]);
      o.z = f2bf(reinterpret_cast<const float*>(&x[2])[q] * sv[2]);
      o.w = f2bf(reinterpret_cast<const float*>(&x[3])[q] * sv[3]);
      *reinterpret_cast<ushort4*>(&XsT[(size_t)(c0 + q) * NN + j0 + j0l]) = o;
    }
  }
}

// ---- kernel 2: numerator partials + fused denominator, pure-register MFMA.
// BM=32 (2 row-frags/wave), 4 waves x 64 cols. Double-buffered register load
// sets pinned with sched_barrier(0) so the allocator cannot serialize them;
// compiler emits counted vmcnt (one full step of slack per set). No LDS/barriers.
struct LoadSet {
  int4 a0l, a0h, a1l, a1h;
  bf16x8 b0, b1, b2, b3, sv;
};

static __device__ __forceinline__ bf16x8 packA(const int4 lo, const int4 hi) {
  union { unsigned u[4]; bf16x8 v; } A;
  A.u[0] = (unsigned)(lo.x + (lo.y << 16)) * 0x3F80u;
  A.u[1] = (unsigned)(lo.z + (lo.w << 16)) * 0x3F80u;
  A.u[2] = (unsigned)(hi.x + (hi.y << 16)) * 0x3F80u;
  A.u[3] = (unsigned)(hi.z + (hi.w << 16)) * 0x3F80u;
  return A.v;
}

__global__ __launch_bounds__(256, 2) void k_gemm(
    const int* __restrict__ adj, const unsigned short* __restrict__ XsT,
    const unsigned short* __restrict__ sT, float* __restrict__ C0,
    float* __restrict__ C1, float* __restrict__ denomPart) {
  const int tid = threadIdx.x;
  const int lane = tid & 63;
  const int wid = tid >> 6;        // col-group 0..3
  const int l15 = lane & 15;
  const int l4 = lane >> 4;        // 0..3

  const int bx = blockIdx.x;
  const int kidx = bx & 1;
  const int rg = bx >> 1;          // 0..255
  const int r0 = rg * 32;
  const int kbeg = kidx * KCH;
  float* __restrict__ Cout = kidx ? C1 : C0;

  const int* pA0 = adj + (size_t)(r0 + l15) * NN + kbeg + l4 * 8;
  const int* pA1 = pA0 + 16 * NN;
  const unsigned short* pB0 = XsT + (size_t)(wid * 64 + 0 + l15) * NN + kbeg + l4 * 8;
  const unsigned short* pB1 = XsT + (size_t)(wid * 64 + 16 + l15) * NN + kbeg + l4 * 8;
  const unsigned short* pB2 = XsT + (size_t)(wid * 64 + 32 + l15) * NN + kbeg + l4 * 8;
  const unsigned short* pB3 = XsT + (size_t)(wid * 64 + 48 + l15) * NN + kbeg + l4 * 8;
  const unsigned short* pS = sT + kbeg + l4 * 8;

  f32x4 acc0[4] = {{0,0,0,0},{0,0,0,0},{0,0,0,0},{0,0,0,0}};
  f32x4 acc1[4] = {{0,0,0,0},{0,0,0,0},{0,0,0,0},{0,0,0,0}};
  f32x4 accD0 = {0,0,0,0}, accD1 = {0,0,0,0};

  LoadSet S0, S1;

#define ISSUE(S, ko)                                                   \
  do {                                                                 \
    (S).a0l = *reinterpret_cast<const int4*>(pA0 + (ko));              \
    (S).a0h = *reinterpret_cast<const int4*>(pA0 + (ko) + 4);          \
    (S).a1l = *reinterpret_cast<const int4*>(pA1 + (ko));              \
    (S).a1h = *reinterpret_cast<const int4*>(pA1 + (ko) + 4);          \
    (S).b0 = *reinterpret_cast<const bf16x8*>(pB0 + (ko));             \
    (S).b1 = *reinterpret_cast<const bf16x8*>(pB1 + (ko));             \
    (S).b2 = *reinterpret_cast<const bf16x8*>(pB2 + (ko));             \
    (S).b3 = *reinterpret_cast<const bf16x8*>(pB3 + (ko));             \
    (S).sv = *reinterpret_cast<const bf16x8*>(pS + (ko));              \
  } while (0)

#define COMPUTE(S)                                                              \
  do {                                                                          \
    bf16x8 A0 = packA((S).a0l, (S).a0h);                                        \
    bf16x8 A1 = packA((S).a1l, (S).a1h);                                        \
    acc0[0] = __builtin_amdgcn_mfma_f32_16x16x32_bf16(A0, (S).b0, acc0[0],0,0,0);\
    acc1[0] = __builtin_amdgcn_mfma_f32_16x16x32_bf16(A1, (S).b0, acc1[0],0,0,0);\
    acc0[1] = __builtin_amdgcn_mfma_f32_16x16x32_bf16(A0, (S).b1, acc0[1],0,0,0);\
    acc1[1] = __builtin_amdgcn_mfma_f32_16x16x32_bf16(A1, (S).b1, acc1[1],0,0,0);\
    acc0[2] = __builtin_amdgcn_mfma_f32_16x16x32_bf16(A0, (S).b2, acc0[2],0,0,0);\
    acc1[2] = __builtin_amdgcn_mfma_f32_16x16x32_bf16(A1, (S).b2, acc1[2],0,0,0);\
    acc0[3] = __builtin_amdgcn_mfma_f32_16x16x32_bf16(A0, (S).b3, acc0[3],0,0,0);\
    acc1[3] = __builtin_amdgcn_mfma_f32_16x16x32_bf16(A1, (S).b3, acc1[3],0,0,0);\
    if (wid == 0) {                                                             \
      accD0 = __builtin_amdgcn_mfma_f32_16x16x32_bf16(A0, (S).sv, accD0,0,0,0); \
      accD1 = __builtin_amdgcn_mfma_f32_16x16x32_bf16(A1, (S).sv, accD1,0,0,0); \
    }                                                                           \
  } while (0)

  ISSUE(S0, 0);
  for (int t = 0; t < KSTEPS; t += 2) {
    ISSUE(S1, (t + 1) * 32);
    __builtin_amdgcn_sched_barrier(0);
    COMPUTE(S0);
    __builtin_amdgcn_sched_barrier(0);
    if (t + 2 < KSTEPS) ISSUE(S0, (t + 2) * 32);
    __builtin_amdgcn_sched_barrier(0);
    COMPUTE(S1);
    __builtin_amdgcn_sched_barrier(0);
  }
#undef ISSUE
#undef COMPUTE

  // epilogue: C/D layout col = lane&15, row = (lane>>4)*4 + q
  const int col0 = wid * 64 + l15;
#pragma unroll
  for (int m = 0; m < 2; m++) {
    const int row0 = r0 + m * 16 + l4 * 4;
    const f32x4* am = m ? acc1 : acc0;
#pragma unroll
    for (int q = 0; q < 4; q++) {
      float* cr = Cout + (size_t)(row0 + q) * DF + col0;
      cr[0]  = am[0][q];
      cr[16] = am[1][q];
      cr[32] = am[2][q];
      cr[48] = am[3][q];
    }
    if (wid == 0 && l15 == 0) {
      const f32x4 ad = m ? accD1 : accD0;
#pragma unroll
      for (int q = 0; q < 4; q++)
        denomPart[kidx * NN + row0 + q] = ad[q];
    }
  }
}

// ---- kernel 3: out = (C0 + C1) / denom   (in place: C0 == d_out)
__global__ void k_norm(float* __restrict__ out, const float* __restrict__ C1,
                       const float* __restrict__ denomPart) {
  int e4 = blockIdx.x * 256 + threadIdx.x;
  size_t base = (size_t)e4 * 4;
  int row = (int)(base >> 8);
  float4 a = *reinterpret_cast<const float4*>(&out[base]);
  float4 b = *reinterpret_cast<const float4*>(&C1[base]);
  float inv = 1.0f / (denomPart[row] + denomPart[NN + row]);
  float4 r;
  r.x = (a.x + b.x) * inv;
  r.y = (a.y + b.y) * inv;
  r.z = (a.z + b.z) * inv;
  r.w = (a.w + b.w) * inv;
  *reinterpret_cast<float4*>(&out[base]) = r;
}

extern "C" void kernel_launch(void* const* d_in, const int* in_sizes, int n_in,
                              void* d_out, int out_size, void* d_ws, size_t ws_size,
                              hipStream_t stream) {
  const float* input = (const float*)d_in[0];
  const int* adj = (const int*)d_in[1];
  const float* A = (const float*)d_in[2];
  float* out = (float*)d_out;

  char* ws = (char*)d_ws;
  unsigned short* sT = (unsigned short*)(ws + 0);       // 16 KB
  float* denomPart = (float*)(ws + 16384);              // 64 KB
  unsigned short* XsT = (unsigned short*)(ws + 81920);  // 4 MB row-major [DF][NN]
  float* C1 = (float*)(ws + 81920 + 4194304);           // 8 MB

  k_pre<<<dim3(NN / 64), dim3(256), 0, stream>>>(input, A, sT, XsT);
  k_gemm<<<dim3((NN / 32) * KSPLIT), dim3(256), 0, stream>>>(adj, XsT, sT, out, C1,
                                                             denomPart);
  k_norm<<<dim3(NN * DF / 1024), dim3(256), 0, stream>>>(out, C1, denomPart);
}